// Round 1
// baseline (964.078 us; speedup 1.0000x reference)
//
#include <hip/hip_runtime.h>
#include <hip/hip_bf16.h>

#define N_NODES_C 100000

// ---------------------------------------------------------------------------
// Kernel 1: edge scatter. 16 threads per edge, one float4 each.
// summed[dst][0:64] += h_src[src][0:64];  deg[dst] += 1
// ---------------------------------------------------------------------------
__global__ __launch_bounds__(256) void scatter_edges(
    const float* __restrict__ h_src,
    const int*   __restrict__ src,
    const int*   __restrict__ dst,
    float*       __restrict__ summed,
    float*       __restrict__ deg,
    int n_edges)
{
    int i = blockIdx.x * 256 + threadIdx.x;
    int total = n_edges * 16;
    if (i >= total) return;
    int e  = i >> 4;
    int f4 = i & 15;
    int s = src[e];
    int d = dst[e];
    float4 v = reinterpret_cast<const float4*>(h_src)[(size_t)s * 16 + f4];
    float* b = summed + (size_t)d * 64 + f4 * 4;
    atomicAdd(b + 0, v.x);
    atomicAdd(b + 1, v.y);
    atomicAdd(b + 2, v.z);
    atomicAdd(b + 3, v.w);
    if (f4 == 0) atomicAdd(deg + d, 1.0f);
}

// ---------------------------------------------------------------------------
// Kernel 2: epilogue GEMM.  out[n][o] = bias[o]
//        + sum_{k<64} h_dst[n][k]*W[o][k]
//        + sum_{k<64} (summed[n][k]/max(deg[n],1))*W[o][64+k]
// Tile: 64 nodes/block, 256 threads, thread tile = 4 nodes x 4 outs.
// LDS: X tile 32KB + W 32KB, both stored as float4 with XOR-rotation swizzle.
// ---------------------------------------------------------------------------
__global__ __launch_bounds__(256) void sage_epilogue(
    const float* __restrict__ h_dst,
    const float* __restrict__ summed,
    const float* __restrict__ deg,
    const float* __restrict__ weight,   // [64][128] row-major
    const float* __restrict__ bias,     // [64]
    float*       __restrict__ out,      // [N][64]
    int n_nodes)
{
    __shared__ float4 x4[64 * 32];   // x4[r][k4] at r*32 + ((k4 + r) & 31)
    __shared__ float4 w4[64 * 32];   // w4[o][k4] at o*32 + ((k4 + (o>>2)) & 31)

    const int t    = threadIdx.x;
    const int base = blockIdx.x * 64;

    // stage W (once per block), swizzled
    #pragma unroll
    for (int q = 0; q < 8; ++q) {
        int idx = t + q * 256;        // 0..2047
        int o   = idx >> 5;
        int k4  = idx & 31;
        float4 wv = reinterpret_cast<const float4*>(weight)[o * 32 + k4];
        w4[o * 32 + ((k4 + (o >> 2)) & 31)] = wv;
    }

    // stage X tile: cols 0..15 from h_dst, cols 16..31 from summed/deg
    #pragma unroll
    for (int q = 0; q < 8; ++q) {
        int idx = t + q * 256;
        int r   = idx >> 5;
        int k4  = idx & 31;
        int g   = base + r;
        float4 xv = make_float4(0.f, 0.f, 0.f, 0.f);
        if (g < n_nodes) {
            if (k4 < 16) {
                xv = reinterpret_cast<const float4*>(h_dst)[(size_t)g * 16 + k4];
            } else {
                float rd = 1.0f / fmaxf(deg[g], 1.0f);
                xv = reinterpret_cast<const float4*>(summed)[(size_t)g * 16 + (k4 - 16)];
                xv.x *= rd; xv.y *= rd; xv.z *= rd; xv.w *= rd;
            }
        }
        x4[r * 32 + ((k4 + r) & 31)] = xv;
    }
    __syncthreads();

    const int m  = t & 15;    // out-group: o0 = 4m
    const int r0 = t >> 4;    // node base: rows r0 + 16*i
    const int o0 = m * 4;

    float4 bv = reinterpret_cast<const float4*>(bias)[m];

    float acc[4][4];
    #pragma unroll
    for (int i = 0; i < 4; ++i) {
        acc[i][0] = bv.x; acc[i][1] = bv.y; acc[i][2] = bv.z; acc[i][3] = bv.w;
    }

    #pragma unroll 4
    for (int k4 = 0; k4 < 32; ++k4) {
        float4 wv[4];
        #pragma unroll
        for (int j = 0; j < 4; ++j) {
            int o = o0 + j;                       // (o>>2) == m for all j
            wv[j] = w4[o * 32 + ((k4 + m) & 31)];
        }
        #pragma unroll
        for (int i = 0; i < 4; ++i) {
            int r = r0 + 16 * i;
            float4 xv = x4[r * 32 + ((k4 + r) & 31)];
            #pragma unroll
            for (int j = 0; j < 4; ++j) {
                acc[i][j] += xv.x * wv[j].x + xv.y * wv[j].y
                           + xv.z * wv[j].z + xv.w * wv[j].w;
            }
        }
    }

    #pragma unroll
    for (int i = 0; i < 4; ++i) {
        int g = base + r0 + 16 * i;
        if (g < n_nodes) {
            float4 ov = make_float4(acc[i][0], acc[i][1], acc[i][2], acc[i][3]);
            reinterpret_cast<float4*>(out)[(size_t)g * 16 + m] = ov;
        }
    }
}

// ---------------------------------------------------------------------------
extern "C" void kernel_launch(void* const* d_in, const int* in_sizes, int n_in,
                              void* d_out, int out_size, void* d_ws, size_t ws_size,
                              hipStream_t stream)
{
    const float* h_src  = (const float*)d_in[0];
    const float* h_dst  = (const float*)d_in[1];
    const int*   src    = (const int*)d_in[2];
    const int*   dst    = (const int*)d_in[3];
    const float* weight = (const float*)d_in[4];
    const float* bias   = (const float*)d_in[5];
    float*       out    = (float*)d_out;

    const int n_edges = in_sizes[2];

    float* summed = (float*)d_ws;                       // [N][64]
    float* deg    = summed + (size_t)N_NODES_C * 64;    // [N]

    // zero accumulators (ws is poisoned, never re-poisoned between replays)
    hipMemsetAsync(d_ws, 0, (size_t)N_NODES_C * 65 * sizeof(float), stream);

    int total = n_edges * 16;
    scatter_edges<<<(total + 255) / 256, 256, 0, stream>>>(
        h_src, src, dst, summed, deg, n_edges);

    sage_epilogue<<<(N_NODES_C + 63) / 64, 256, 0, stream>>>(
        h_dst, summed, deg, weight, bias, out, N_NODES_C);
}

// Round 2
// 213.238 us; speedup vs baseline: 4.5211x; 4.5211x over previous
//
#include <hip/hip_runtime.h>
#include <hip/hip_bf16.h>

#define N_NODES_C 100000
#define NSCAN     102400      // N padded to 25 * 4096 for the scan
#define SCAN_BS   1024        // threads per scan block (4 elems each -> 4096/block)
#define NB_SCAN   (NSCAN / (SCAN_BS * 4))   // 25 blocks

// ---------------------------------------------------------------------------
// CSR build: histogram -> block scan -> partials scan -> add -> fill
// ---------------------------------------------------------------------------
__global__ __launch_bounds__(256) void edge_hist(
    const int* __restrict__ dst, int* __restrict__ counts, int n_edges)
{
    int e = blockIdx.x * 256 + threadIdx.x;
    if (e < n_edges) atomicAdd(&counts[dst[e]], 1);
}

__global__ __launch_bounds__(SCAN_BS) void scan_block(
    const int* __restrict__ counts, int* __restrict__ offsets,
    int* __restrict__ partials)
{
    __shared__ int sd[2][SCAN_BS];
    int t = threadIdx.x, b = blockIdx.x;
    int4 c = reinterpret_cast<const int4*>(counts)[b * SCAN_BS + t];
    int tot = c.x + c.y + c.z + c.w;
    sd[0][t] = tot;
    __syncthreads();
    int pin = 0;
    #pragma unroll
    for (int off = 1; off < SCAN_BS; off <<= 1) {
        int v = sd[pin][t];
        if (t >= off) v += sd[pin][t - off];
        sd[pin ^ 1][t] = v;
        pin ^= 1;
        __syncthreads();
    }
    int incl = sd[pin][t];      // inclusive scan of per-thread sums
    int excl = incl - tot;
    int4 o;
    o.x = excl;
    o.y = excl + c.x;
    o.z = excl + c.x + c.y;
    o.w = excl + c.x + c.y + c.z;
    reinterpret_cast<int4*>(offsets)[b * SCAN_BS + t] = o;
    if (t == SCAN_BS - 1) partials[b] = incl;
}

__global__ void scan_partials(int* __restrict__ partials, int nb)
{
    if (threadIdx.x == 0 && blockIdx.x == 0) {
        int run = 0;
        for (int i = 0; i < nb; ++i) {
            int v = partials[i];
            partials[i] = run;
            run += v;
        }
    }
}

__global__ __launch_bounds__(256) void scan_add(
    int* __restrict__ offsets, int* __restrict__ cursors,
    const int* __restrict__ partials)
{
    int i = blockIdx.x * 256 + threadIdx.x;
    if (i < NSCAN) {
        int v = offsets[i] + partials[i >> 12];   // i/4096
        offsets[i] = v;
        cursors[i] = v;
    }
}

__global__ __launch_bounds__(256) void edge_fill(
    const int* __restrict__ src, const int* __restrict__ dst,
    int* __restrict__ cursors, int* __restrict__ edge_src, int n_edges)
{
    int e = blockIdx.x * 256 + threadIdx.x;
    if (e < n_edges) {
        int d = dst[e];
        int pos = atomicAdd(&cursors[d], 1);
        edge_src[pos] = src[e];
    }
}

// ---------------------------------------------------------------------------
// Fused gather-mean + GEMM.
// Block: 256 threads, 64 nodes. LDS: X tile 32KB + W 32KB (swizzled float4).
// x[r][0:16)  = h_dst row           (k4 = 0..15)
// x[r][16:32) = mean of neighbors   (k4 = 16..31), gathered via CSR
// out[n][o] = bias[o] + sum_k x[n][k] * W[o][k]
// ---------------------------------------------------------------------------
__global__ __launch_bounds__(256) void sage_fused(
    const float* __restrict__ h_src,
    const float* __restrict__ h_dst,
    const int*   __restrict__ offsets,
    const int*   __restrict__ edge_src,
    const float* __restrict__ weight,   // [64][128] row-major
    const float* __restrict__ bias,     // [64]
    float*       __restrict__ out,      // [N][64]
    int n_nodes)
{
    __shared__ float4 x4[64 * 32];   // x4[r][k4] at r*32 + ((k4 + r) & 31)
    __shared__ float4 w4[64 * 32];   // w4[o][k4] at o*32 + ((k4 + (o>>2)) & 31)

    const int t    = threadIdx.x;
    const int base = blockIdx.x * 64;

    // stage W, swizzled
    #pragma unroll
    for (int q = 0; q < 8; ++q) {
        int idx = t + q * 256;        // 0..2047
        int o   = idx >> 5;
        int k4  = idx & 31;
        float4 wv = reinterpret_cast<const float4*>(weight)[o * 32 + k4];
        w4[o * 32 + ((k4 + (o >> 2)) & 31)] = wv;
    }

    // stage h_dst (cols 0..15)
    #pragma unroll
    for (int q = 0; q < 4; ++q) {
        int idx = t + q * 256;        // 0..1023
        int r   = idx >> 4;
        int k4  = idx & 15;
        int g   = base + r;
        float4 xv = make_float4(0.f, 0.f, 0.f, 0.f);
        if (g < n_nodes)
            xv = reinterpret_cast<const float4*>(h_dst)[(size_t)g * 16 + k4];
        x4[r * 32 + ((k4 + r) & 31)] = xv;
    }

    // gather neighbor mean (cols 16..31): 4 threads per node
    {
        const int j = t & 3;          // float4 lane group within row
        const int r = t >> 2;         // node within tile (0..63)
        const int g = base + r;
        float4 a0 = make_float4(0.f, 0.f, 0.f, 0.f);
        float4 a1 = a0, a2 = a0, a3 = a0;
        float invd = 0.f;
        if (g < n_nodes) {
            int e0 = offsets[g];
            int e1 = offsets[g + 1];
            int s  = (e0 < e1) ? edge_src[e0] : 0;
            for (int e = e0; e < e1; ++e) {
                int sn = (e + 1 < e1) ? edge_src[e + 1] : 0;
                const float4* row = reinterpret_cast<const float4*>(h_src) + (size_t)s * 16;
                float4 v0 = row[j +  0];
                float4 v1 = row[j +  4];
                float4 v2 = row[j +  8];
                float4 v3 = row[j + 12];
                a0.x += v0.x; a0.y += v0.y; a0.z += v0.z; a0.w += v0.w;
                a1.x += v1.x; a1.y += v1.y; a1.z += v1.z; a1.w += v1.w;
                a2.x += v2.x; a2.y += v2.y; a2.z += v2.z; a2.w += v2.w;
                a3.x += v3.x; a3.y += v3.y; a3.z += v3.z; a3.w += v3.w;
                s = sn;
            }
            int degv = e1 - e0;
            invd = 1.0f / (float)(degv > 1 ? degv : 1);
        }
        a0.x *= invd; a0.y *= invd; a0.z *= invd; a0.w *= invd;
        a1.x *= invd; a1.y *= invd; a1.z *= invd; a1.w *= invd;
        a2.x *= invd; a2.y *= invd; a2.z *= invd; a2.w *= invd;
        a3.x *= invd; a3.y *= invd; a3.z *= invd; a3.w *= invd;
        x4[r * 32 + (((16 + j +  0) + r) & 31)] = a0;
        x4[r * 32 + (((16 + j +  4) + r) & 31)] = a1;
        x4[r * 32 + (((16 + j +  8) + r) & 31)] = a2;
        x4[r * 32 + (((16 + j + 12) + r) & 31)] = a3;
    }
    __syncthreads();

    // GEMM: thread tile = 4 nodes x 4 outs
    const int m  = t & 15;    // out-group: o0 = 4m
    const int r0 = t >> 4;    // node base: rows r0 + 16*i
    const int o0 = m * 4;

    float4 bv = reinterpret_cast<const float4*>(bias)[m];

    float acc[4][4];
    #pragma unroll
    for (int i = 0; i < 4; ++i) {
        acc[i][0] = bv.x; acc[i][1] = bv.y; acc[i][2] = bv.z; acc[i][3] = bv.w;
    }

    #pragma unroll 4
    for (int k4 = 0; k4 < 32; ++k4) {
        float4 wv[4];
        #pragma unroll
        for (int jj = 0; jj < 4; ++jj) {
            int o = o0 + jj;                      // (o>>2) == m for all jj
            wv[jj] = w4[o * 32 + ((k4 + m) & 31)];
        }
        #pragma unroll
        for (int i = 0; i < 4; ++i) {
            int r = r0 + 16 * i;
            float4 xv = x4[r * 32 + ((k4 + r) & 31)];
            #pragma unroll
            for (int jj = 0; jj < 4; ++jj) {
                acc[i][jj] += xv.x * wv[jj].x + xv.y * wv[jj].y
                            + xv.z * wv[jj].z + xv.w * wv[jj].w;
            }
        }
    }

    #pragma unroll
    for (int i = 0; i < 4; ++i) {
        int g = base + r0 + 16 * i;
        if (g < n_nodes) {
            float4 ov = make_float4(acc[i][0], acc[i][1], acc[i][2], acc[i][3]);
            reinterpret_cast<float4*>(out)[(size_t)g * 16 + m] = ov;
        }
    }
}

// ---------------------------------------------------------------------------
extern "C" void kernel_launch(void* const* d_in, const int* in_sizes, int n_in,
                              void* d_out, int out_size, void* d_ws, size_t ws_size,
                              hipStream_t stream)
{
    const float* h_src  = (const float*)d_in[0];
    const float* h_dst  = (const float*)d_in[1];
    const int*   src    = (const int*)d_in[2];
    const int*   dst    = (const int*)d_in[3];
    const float* weight = (const float*)d_in[4];
    const float* bias   = (const float*)d_in[5];
    float*       out    = (float*)d_out;

    const int n_edges = in_sizes[2];

    // workspace layout (ints)
    int* counts   = (int*)d_ws;            // NSCAN
    int* offsets  = counts   + NSCAN;      // NSCAN  (offsets[N] valid)
    int* cursors  = offsets  + NSCAN;      // NSCAN
    int* partials = cursors  + NSCAN;      // 64
    int* edge_src = partials + 64;         // n_edges

    // zero the histogram (ws is poisoned; everything else is fully rewritten)
    hipMemsetAsync(counts, 0, NSCAN * sizeof(int), stream);

    int nbE = (n_edges + 255) / 256;
    edge_hist<<<nbE, 256, 0, stream>>>(dst, counts, n_edges);
    scan_block<<<NB_SCAN, SCAN_BS, 0, stream>>>(counts, offsets, partials);
    scan_partials<<<1, 64, 0, stream>>>(partials, NB_SCAN);
    scan_add<<<NSCAN / 256, 256, 0, stream>>>(offsets, cursors, partials);
    edge_fill<<<nbE, 256, 0, stream>>>(src, dst, cursors, edge_src, n_edges);

    sage_fused<<<(N_NODES_C + 63) / 64, 256, 0, stream>>>(
        h_src, h_dst, offsets, edge_src, weight, bias, out, N_NODES_C);
}